// Round 4
// baseline (263.678 us; speedup 1.0000x reference)
//
#include <hip/hip_runtime.h>

#define NROWS 8192
#define DDIM 256
#define BT 128
#define BK 64
#define GT (NROWS / BT)            // 64 tile-rows
#define NBT (GT * (GT + 1) / 2)    // 2080 upper-triangle blocks
#define NCLS 512
#define NTOT (NCLS + NBT)          // 2592 blocks in main kernel
#define LCAP 64                    // max rows per class cached (mean 16, max ~30)

using bf16x8 = __attribute__((ext_vector_type(8))) __bf16;
using u16x8  = __attribute__((ext_vector_type(8))) unsigned short;
using f32x4  = __attribute__((ext_vector_type(4))) float;

__device__ __forceinline__ void glds16(const unsigned short* g, unsigned short* l) {
    // async global->LDS DMA, 16B/lane; LDS dest = wave-uniform base + lane*16
    __builtin_amdgcn_global_load_lds(
        (const __attribute__((address_space(1))) unsigned int*)g,
        (__attribute__((address_space(3))) unsigned int*)l,
        16, 0, 0);
}

__device__ __forceinline__ unsigned short f2bf(float f) {
    unsigned int b = __float_as_uint(f);
    unsigned int r = b + 0x7fffu + ((b >> 16) & 1u);
    return (unsigned short)(r >> 16);
}
__device__ __forceinline__ float bf2f(unsigned short u) {
    return __uint_as_float((unsigned)u << 16);
}

// accum layout (floats): 0 sAll, 1 cAll, 2 sSub, 3 cSub, 4 sPos, 5 cPos, 6 rr, 7 done(uint bits)

// Kernel 1: one wave per row. Normalize, CENTER (e - mean), emit bf16 e~,
// per-row epilogue constants, and zero the global accumulators.
//   dist_ij = (b_i + b_j - (e~_i . e~_j)/128) / b_i
//   v_neg(i,j) = 0.2 - dist_ij = fmaf(aP_i, raw + bs_j, c_i)
//   with aP = (1/b)/128, bs = -128*b, c = aP*bs + 0.2
__global__ __launch_bounds__(256) void rowstats_kernel(
    const float* __restrict__ x, unsigned short* __restrict__ ebf,
    float* __restrict__ aP, float* __restrict__ bs,
    float* __restrict__ cA, float* __restrict__ rabs,
    float* __restrict__ accum)
{
    if (blockIdx.x == 0 && threadIdx.x < 8) accum[threadIdx.x] = 0.0f;

    int wave = threadIdx.x >> 6;
    int lane = threadIdx.x & 63;
    int row  = blockIdx.x * 4 + wave;

    const float4 v = reinterpret_cast<const float4*>(x + (size_t)row * DDIM)[lane];
    float ss = v.x * v.x + v.y * v.y + v.z * v.z + v.w * v.w;
    float sm = v.x + v.y + v.z + v.w;
    #pragma unroll
    for (int off = 32; off >= 1; off >>= 1) {
        ss += __shfl_xor(ss, off);
        sm += __shfl_xor(sm, off);
    }
    float invn = 1.0f / sqrtf(ss);
    float m = sm * invn * (1.0f / DDIM);

    ushort4 o;
    o.x = f2bf(v.x * invn - m);
    o.y = f2bf(v.y * invn - m);
    o.z = f2bf(v.z * invn - m);
    o.w = f2bf(v.w * invn - m);
    reinterpret_cast<ushort4*>(ebf + (size_t)row * DDIM)[lane] = o;

    if (lane == 0) {
        float s  = ss * invn * invn * (1.0f / DDIM);
        float b  = s - m * m;
        float a  = 1.0f / b;
        float ap = a * (1.0f / 128.0f);
        float bv = -128.0f * b;
        aP[row]   = ap;
        bs[row]   = bv;
        cA[row]   = fmaf(ap, bv, 0.2f);
        rabs[row] = fabsf(sm * invn);
    }
}

// Kernel 2 (fused, single node for everything else):
//   blocks [0, NCLS): sparse same-label correction (LDS row cache, 16-lane groups)
//                     + rabs partial sums.
//   blocks [NCLS, NTOT): upper-triangle E~.E~^T bf16 MFMA GEMM, label-free
//                        neg-only epilogue.
//   All blocks atomicAdd partials into accum[]; the last block to finish
//   computes the final scalar loss (device-scope last-block-done pattern).
__global__ __launch_bounds__(256, 4) void snr_main_kernel(
    const unsigned short* __restrict__ ebf,
    const float* __restrict__ aP, const float* __restrict__ bs,
    const float* __restrict__ cA, const int* __restrict__ labels,
    const float* __restrict__ rabs,
    float* __restrict__ accum, float* __restrict__ out)
{
    __shared__ __align__(16) unsigned short smem[BT * BK * 2];  // 32 KB: As|Bs or corr row cache
    __shared__ float sAPi[BT], sBsi[BT], sCi[BT];
    __shared__ float sAPj[BT], sBsj[BT], sCj[BT];
    __shared__ float redbuf[4][4];
    __shared__ int rowsL[LCAP];
    __shared__ int cntS;

    int tid  = threadIdx.x;
    int lane = tid & 63;
    int wave = tid >> 6;

    if (blockIdx.x < NCLS) {
        // ---------------- corr path: one block per label ----------------
        int L = blockIdx.x;
        if (tid == 0) cntS = 0;
        __syncthreads();
        for (int i = tid; i < NROWS; i += 256)
            if (labels[i] == L) { int p = atomicAdd(&cntS, 1); if (p < LCAP) rowsL[p] = i; }
        __syncthreads();
        int n = min(cntS, LCAP);

        // stage class rows into LDS cache (coalesced; 1 ushort4 per lane per row)
        unsigned short* rc = smem;
        for (int r = wave; r < n; r += 4) {
            ushort4 t4 = reinterpret_cast<const ushort4*>(ebf + (size_t)rowsL[r] * DDIM)[lane];
            reinterpret_cast<ushort4*>(rc + r * DDIM)[lane] = t4;
        }
        if (tid < n) {
            sAPi[tid] = aP[rowsL[tid]];
            sBsi[tid] = bs[rowsL[tid]];
            sCi[tid]  = cA[rowsL[tid]];
        }
        // rabs partial: block L owns rows [L*16, L*16+16)
        float rrp = (tid < 16) ? rabs[L * 16 + tid] : 0.f;
        rrp += __shfl_down(rrp, 8);
        rrp += __shfl_down(rrp, 4);
        rrp += __shfl_down(rrp, 2);
        rrp += __shfl_down(rrp, 1);
        __syncthreads();

        // 16 groups of 16 lanes; each group owns one unordered pair per round
        int grp = tid >> 4;
        int l16 = tid & 15;
        int T = n * (n + 1) / 2;   // unordered pairs incl. diagonal
        float Ssub = 0.f, Spos = 0.f, Csub = 0.f, Cpos = 0.f;

        for (int p = grp; p < T; p += 16) {
            int r1 = (int)((sqrtf(8.0f * (float)p + 1.0f) - 1.0f) * 0.5f);
            while ((r1 + 1) * (r1 + 2) / 2 <= p) ++r1;
            while (r1 * (r1 + 1) / 2 > p) --r1;
            int c = p - r1 * (r1 + 1) / 2;

            const unsigned short* ru = rc + r1 * DDIM + l16 * 16;
            const unsigned short* rv = rc + c  * DDIM + l16 * 16;
            float d = 0.f;
            #pragma unroll
            for (int h = 0; h < 2; ++h) {
                u16x8 a8 = *reinterpret_cast<const u16x8*>(ru + h * 8);
                u16x8 b8 = *reinterpret_cast<const u16x8*>(rv + h * 8);
                #pragma unroll
                for (int e = 0; e < 8; ++e)
                    d = fmaf(bf2f(a8[e]), bf2f(b8[e]), d);
            }
            d += __shfl_xor(d, 1);
            d += __shfl_xor(d, 2);
            d += __shfl_xor(d, 4);
            d += __shfl_xor(d, 8);

            if (l16 == 0) {
                // match the main epilogue's formula shape for best cancellation
                float vn1 = fmaf(sAPi[r1], d + sBsi[c],  sCi[r1]);   // v_neg(u,v)
                if (r1 == c) {
                    // diagonal: main counted it once as a neg; no pos term
                    Ssub += fmaxf(vn1, 0.f); Csub += (vn1 > 0.f);
                } else {
                    float vn2 = fmaf(sAPi[c], d + sBsi[r1], sCi[c]); // v_neg(v,u)
                    Ssub += fmaxf(vn1, 0.f) + fmaxf(vn2, 0.f);
                    Csub += (vn1 > 0.f); Csub += (vn2 > 0.f);
                    float rawfull = d + sBsi[r1] + sBsi[c];
                    float vp1 = fmaf(-sAPi[r1], rawfull, -0.01f);    // d_uv - 0.01
                    float vp2 = fmaf(-sAPi[c],  rawfull, -0.01f);    // d_vu - 0.01
                    Spos += fmaxf(vp1, 0.f) + fmaxf(vp2, 0.f);
                    Cpos += (vp1 > 0.f); Cpos += (vp2 > 0.f);
                }
            }
        }

        #pragma unroll
        for (int off = 32; off >= 1; off >>= 1) {
            Ssub += __shfl_down(Ssub, off);
            Csub += __shfl_down(Csub, off);
            Spos += __shfl_down(Spos, off);
            Cpos += __shfl_down(Cpos, off);
        }
        if (lane == 0) {
            redbuf[wave][0] = Ssub; redbuf[wave][1] = Csub;
            redbuf[wave][2] = Spos; redbuf[wave][3] = Cpos;
        }
        __syncthreads();
        if (tid == 0) {
            float a0 = redbuf[0][0] + redbuf[1][0] + redbuf[2][0] + redbuf[3][0];
            float a1 = redbuf[0][1] + redbuf[1][1] + redbuf[2][1] + redbuf[3][1];
            float a2 = redbuf[0][2] + redbuf[1][2] + redbuf[2][2] + redbuf[3][2];
            float a3 = redbuf[0][3] + redbuf[1][3] + redbuf[2][3] + redbuf[3][3];
            atomicAdd(accum + 2, a0);
            atomicAdd(accum + 3, a1);
            atomicAdd(accum + 4, a2);
            atomicAdd(accum + 5, a3);
            atomicAdd(accum + 6, rrp);
        }
    } else {
        // ---------------- GEMM path ----------------
        unsigned short* As = smem;
        unsigned short* Bs = smem + BT * BK;
        int wr = (wave >> 1) * 64;
        int wc = (wave & 1) * 64;

        // decode triangular block id -> (bi, bj), bi <= bj
        int t = blockIdx.x - NCLS;
        int bi = (int)((2.0f * GT + 1.0f
                        - sqrtf((2.0f * GT + 1.0f) * (2.0f * GT + 1.0f) - 8.0f * (float)t)) * 0.5f);
        while ((bi + 1) * GT - ((bi + 1) * bi) / 2 <= t) ++bi;
        while (bi * GT - (bi * (bi - 1)) / 2 > t) --bi;
        int bj = bi + (t - (bi * GT - (bi * (bi - 1)) / 2));
        int rowBase = bi * BT, colBase = bj * BT;
        bool diag = (bi == bj);

        // stage per-row / per-col epilogue constants (covered by first K-loop barrier)
        if (tid < BT) {
            int gi = rowBase + tid;
            sAPi[tid] = aP[gi]; sBsi[tid] = bs[gi]; sCi[tid] = cA[gi];
        } else {
            int tt = tid - BT;
            int gj = colBase + tt;
            sAPj[tt] = aP[gj]; sBsj[tt] = bs[gj]; sCj[tt] = cA[gj];
        }

        // staging addresses: chunk q = p*256+tid; logical (row=q>>3, slot=q&7),
        // slot holds k-chunk kc = slot ^ (row&7)  (XOR swizzle, conflict-free frag reads)
        const unsigned short* gA[4];
        const unsigned short* gB[4];
        unsigned short* lpA[4];
        unsigned short* lpB[4];
        #pragma unroll
        for (int p = 0; p < 4; ++p) {
            int q   = p * 256 + tid;
            int row = q >> 3;
            int kc  = (q & 7) ^ (row & 7);
            gA[p] = ebf + (size_t)(rowBase + row) * DDIM + kc * 8;
            gB[p] = ebf + (size_t)(colBase + row) * DDIM + kc * 8;
            lpA[p] = As + q * 8;
            lpB[p] = Bs + q * 8;
        }

        // fragment LDS offsets (elems), swizzle-aware
        int mrow = lane & 15;
        int kch  = lane >> 4;          // 16B k-chunk within half
        int offA[4][2], offB[4][2];
        #pragma unroll
        for (int t4 = 0; t4 < 4; ++t4) {
            int rA = wr + t4 * 16 + mrow;
            int rB = wc + t4 * 16 + mrow;
            #pragma unroll
            for (int h = 0; h < 2; ++h) {
                offA[t4][h] = (rA * 8 + ((h * 4 + kch) ^ (rA & 7))) * 8;
                offB[t4][h] = (rB * 8 + ((h * 4 + kch) ^ (rB & 7))) * 8;
            }
        }

        f32x4 acc[4][4];
        #pragma unroll
        for (int a = 0; a < 4; ++a)
            #pragma unroll
            for (int b = 0; b < 4; ++b)
                acc[a][b] = (f32x4){0.f, 0.f, 0.f, 0.f};

        for (int it = 0; it < 4; ++it) {
            #pragma unroll
            for (int p = 0; p < 4; ++p) {
                glds16(gA[p], lpA[p]);
                glds16(gB[p], lpB[p]);
                gA[p] += BK;
                gB[p] += BK;
            }
            asm volatile("s_waitcnt vmcnt(0)" ::: "memory");
            __syncthreads();

            #pragma unroll
            for (int h = 0; h < 2; ++h) {
                bf16x8 aF[4], bF[4];
                #pragma unroll
                for (int t4 = 0; t4 < 4; ++t4) {
                    aF[t4] = *reinterpret_cast<const bf16x8*>(As + offA[t4][h]);
                    bF[t4] = *reinterpret_cast<const bf16x8*>(Bs + offB[t4][h]);
                }
                #pragma unroll
                for (int ti = 0; ti < 4; ++ti)
                    #pragma unroll
                    for (int tj = 0; tj < 4; ++tj)
                        acc[ti][tj] = __builtin_amdgcn_mfma_f32_16x16x32_bf16(aF[ti], bF[tj], acc[ti][tj], 0, 0, 0);
            }
            __syncthreads();
        }

        // Epilogue: neg treatment for EVERY ordered pair (no labels here).
        // v_neg(i,j) = fmaf(aP_i, raw + bs_j, c_i);  off-diag blocks do both sides.
        int subr = (lane >> 4) * 4;
        int cj   = lane & 15;

        float aPC[4], bsC[4], cC[4];
        #pragma unroll
        for (int tj = 0; tj < 4; ++tj) {
            int lj = wc + tj * 16 + cj;
            aPC[tj] = sAPj[lj]; bsC[tj] = sBsj[lj]; cC[tj] = sCj[lj];
        }

        float S = 0.f;
        unsigned C = 0u;

        if (!diag) {
            #pragma unroll
            for (int ti = 0; ti < 4; ++ti) {
                #pragma unroll
                for (int r = 0; r < 4; ++r) {
                    int li = wr + ti * 16 + subr + r;
                    float aR = sAPi[li], bR = sBsi[li], cR = sCi[li];
                    #pragma unroll
                    for (int tj = 0; tj < 4; ++tj) {
                        float raw = acc[ti][tj][r];
                        float v1 = fmaf(aR, raw + bsC[tj], cR);       // side (i,j)
                        float v2 = fmaf(aPC[tj], raw + bR, cC[tj]);   // side (j,i)
                        S += fmaxf(v1, 0.f) + fmaxf(v2, 0.f);
                        C += (v1 > 0.f);
                        C += (v2 > 0.f);
                    }
                }
            }
        } else {
            #pragma unroll
            for (int ti = 0; ti < 4; ++ti) {
                #pragma unroll
                for (int r = 0; r < 4; ++r) {
                    int li = wr + ti * 16 + subr + r;
                    float aR = sAPi[li], cR = sCi[li];
                    #pragma unroll
                    for (int tj = 0; tj < 4; ++tj) {
                        float raw = acc[ti][tj][r];
                        float v1 = fmaf(aR, raw + bsC[tj], cR);
                        S += fmaxf(v1, 0.f);
                        C += (v1 > 0.f);
                    }
                }
            }
        }

        #pragma unroll
        for (int off = 32; off >= 1; off >>= 1) {
            S += __shfl_down(S, off);
            C += __shfl_down(C, off);
        }
        if (lane == 0) { redbuf[wave][0] = S; redbuf[wave][1] = (float)C; }
        __syncthreads();
        if (tid == 0) {
            float a0 = redbuf[0][0] + redbuf[1][0] + redbuf[2][0] + redbuf[3][0];
            float a1 = redbuf[0][1] + redbuf[1][1] + redbuf[2][1] + redbuf[3][1];
            atomicAdd(accum + 0, a0);
            atomicAdd(accum + 1, a1);
        }
    }

    // ---------------- last-block-done finalize ----------------
    if (tid == 0) {
        __threadfence();
        unsigned old = atomicAdd((unsigned*)(accum + 7), 1u);
        if (old == NTOT - 1) {
            // coherent reads of the accumulators via device-scope RMW
            float sAll = atomicAdd(accum + 0, 0.f);
            float cAll = atomicAdd(accum + 1, 0.f);
            float sSub = atomicAdd(accum + 2, 0.f);
            float cSub = atomicAdd(accum + 3, 0.f);
            float sPos = atomicAdd(accum + 4, 0.f);
            float cPos = atomicAdd(accum + 5, 0.f);
            float rr   = atomicAdd(accum + 6, 0.f);
            float Sn = sAll - sSub;
            float Cn = cAll - cSub;
            // guard: count==0 -> reference yields sum/1e-12 with sum==0 -> 0
            float pos = (cPos > 0.5f) ? sPos / (cPos + 1e-12f) : 0.0f;
            float neg = (Cn   > 0.5f) ? Sn   / (Cn   + 1e-12f) : 0.0f;
            out[0] = pos + neg + rr * (0.1f / (float)NROWS);
        }
    }
}

extern "C" void kernel_launch(void* const* d_in, const int* in_sizes, int n_in,
                              void* d_out, int out_size, void* d_ws, size_t ws_size,
                              hipStream_t stream) {
    const float* embeds = (const float*)d_in[0];
    const int*   labels = (const int*)d_in[1];
    float* out = (float*)d_out;

    char* ws = (char*)d_ws;
    unsigned short* ebf = (unsigned short*)ws;                       // 4 MB
    float* aP    = (float*)(ws + (size_t)NROWS * DDIM * 2);
    float* bs    = aP + NROWS;
    float* cA    = bs + NROWS;
    float* rabs  = cA + NROWS;
    float* accum = rabs + NROWS;                                     // 8 floats

    rowstats_kernel<<<NROWS / 4, 256, 0, stream>>>(embeds, ebf, aP, bs, cA, rabs, accum);

    snr_main_kernel<<<NTOT, 256, 0, stream>>>(ebf, aP, bs, cA, labels, rabs, accum, out);
}

// Round 5
// 200.912 us; speedup vs baseline: 1.3124x; 1.3124x over previous
//
#include <hip/hip_runtime.h>

#define NROWS 8192
#define DDIM 256
#define BT 128
#define BK 64
#define GT (NROWS / BT)            // 64 tile-rows
#define NBT (GT * (GT + 1) / 2)    // 2080 upper-triangle blocks
#define NCLS 512
#define NTOT (NCLS + NBT)          // 2592 blocks in main kernel
#define LCAP 64                    // max rows per class cached (mean 16, max ~30)

using bf16x8 = __attribute__((ext_vector_type(8))) __bf16;
using u16x8  = __attribute__((ext_vector_type(8))) unsigned short;
using f32x4  = __attribute__((ext_vector_type(4))) float;

__device__ __forceinline__ void glds16(const unsigned short* g, unsigned short* l) {
    // async global->LDS DMA, 16B/lane; LDS dest = wave-uniform base + lane*16
    __builtin_amdgcn_global_load_lds(
        (const __attribute__((address_space(1))) unsigned int*)g,
        (__attribute__((address_space(3))) unsigned int*)l,
        16, 0, 0);
}

__device__ __forceinline__ unsigned short f2bf(float f) {
    unsigned int b = __float_as_uint(f);
    unsigned int r = b + 0x7fffu + ((b >> 16) & 1u);
    return (unsigned short)(r >> 16);
}
__device__ __forceinline__ float bf2f(unsigned short u) {
    return __uint_as_float((unsigned)u << 16);
}

// accum layout (floats): 0 sAll, 1 cAll, 2 sSub, 3 cSub, 4 sPos, 5 cPos, 6 rr, 7 done(uint bits)

// Kernel 1: one wave per row. Normalize, CENTER (e - mean), emit bf16 e~,
// per-row epilogue constants, and zero the global accumulators.
//   dist_ij = (b_i + b_j - (e~_i . e~_j)/128) / b_i
//   v_neg(i,j) = 0.2 - dist_ij = fmaf(aP_i, raw + bs_j, c_i)
//   with aP = (1/b)/128, bs = -128*b, c = aP*bs + 0.2
__global__ __launch_bounds__(256) void rowstats_kernel(
    const float* __restrict__ x, unsigned short* __restrict__ ebf,
    float* __restrict__ aP, float* __restrict__ bs,
    float* __restrict__ cA, float* __restrict__ rabs,
    float* __restrict__ accum)
{
    if (blockIdx.x == 0 && threadIdx.x < 8) accum[threadIdx.x] = 0.0f;

    int wave = threadIdx.x >> 6;
    int lane = threadIdx.x & 63;
    int row  = blockIdx.x * 4 + wave;

    const float4 v = reinterpret_cast<const float4*>(x + (size_t)row * DDIM)[lane];
    float ss = v.x * v.x + v.y * v.y + v.z * v.z + v.w * v.w;
    float sm = v.x + v.y + v.z + v.w;
    #pragma unroll
    for (int off = 32; off >= 1; off >>= 1) {
        ss += __shfl_xor(ss, off);
        sm += __shfl_xor(sm, off);
    }
    float invn = 1.0f / sqrtf(ss);
    float m = sm * invn * (1.0f / DDIM);

    ushort4 o;
    o.x = f2bf(v.x * invn - m);
    o.y = f2bf(v.y * invn - m);
    o.z = f2bf(v.z * invn - m);
    o.w = f2bf(v.w * invn - m);
    reinterpret_cast<ushort4*>(ebf + (size_t)row * DDIM)[lane] = o;

    if (lane == 0) {
        float s  = ss * invn * invn * (1.0f / DDIM);
        float b  = s - m * m;
        float a  = 1.0f / b;
        float ap = a * (1.0f / 128.0f);
        float bv = -128.0f * b;
        aP[row]   = ap;
        bs[row]   = bv;
        cA[row]   = fmaf(ap, bv, 0.2f);
        rabs[row] = fabsf(sm * invn);
    }
}

// Kernel 2 (fused, single node for everything else):
//   blocks [0, NCLS): sparse same-label correction (LDS row cache, 16-lane groups)
//                     + rabs partial sums.
//   blocks [NCLS, NTOT): upper-triangle E~.E~^T bf16 MFMA GEMM, label-free
//                        neg-only epilogue.
//   All blocks atomicAdd partials into accum[]; the last block to finish
//   computes the final scalar loss (device-scope last-block-done pattern).
// NOTE: plain __launch_bounds__(256) — a (256,4) min-waves floor made the
// allocator clamp to 64 VGPR and spill acc[][] to scratch (229 MB writes, 2.4x slower).
__global__ __launch_bounds__(256) void snr_main_kernel(
    const unsigned short* __restrict__ ebf,
    const float* __restrict__ aP, const float* __restrict__ bs,
    const float* __restrict__ cA, const int* __restrict__ labels,
    const float* __restrict__ rabs,
    float* __restrict__ accum, float* __restrict__ out)
{
    __shared__ __align__(16) unsigned short smem[BT * BK * 2];  // 32 KB: As|Bs or corr row cache
    __shared__ float sAPi[BT], sBsi[BT], sCi[BT];
    __shared__ float sAPj[BT], sBsj[BT], sCj[BT];
    __shared__ float redbuf[4][4];
    __shared__ int rowsL[LCAP];
    __shared__ int cntS;

    int tid  = threadIdx.x;
    int lane = tid & 63;
    int wave = tid >> 6;

    if (blockIdx.x < NCLS) {
        // ---------------- corr path: one block per label ----------------
        int L = blockIdx.x;
        if (tid == 0) cntS = 0;
        __syncthreads();
        for (int i = tid; i < NROWS; i += 256)
            if (labels[i] == L) { int p = atomicAdd(&cntS, 1); if (p < LCAP) rowsL[p] = i; }
        __syncthreads();
        int n = min(cntS, LCAP);

        // stage class rows into LDS cache (coalesced; 1 ushort4 per lane per row)
        unsigned short* rc = smem;
        for (int r = wave; r < n; r += 4) {
            ushort4 t4 = reinterpret_cast<const ushort4*>(ebf + (size_t)rowsL[r] * DDIM)[lane];
            reinterpret_cast<ushort4*>(rc + r * DDIM)[lane] = t4;
        }
        if (tid < n) {
            sAPi[tid] = aP[rowsL[tid]];
            sBsi[tid] = bs[rowsL[tid]];
            sCi[tid]  = cA[rowsL[tid]];
        }
        // rabs partial: block L owns rows [L*16, L*16+16)
        float rrp = (tid < 16) ? rabs[L * 16 + tid] : 0.f;
        rrp += __shfl_down(rrp, 8);
        rrp += __shfl_down(rrp, 4);
        rrp += __shfl_down(rrp, 2);
        rrp += __shfl_down(rrp, 1);
        __syncthreads();

        // 16 groups of 16 lanes; each group owns one unordered pair per round
        int grp = tid >> 4;
        int l16 = tid & 15;
        int T = n * (n + 1) / 2;   // unordered pairs incl. diagonal
        float Ssub = 0.f, Spos = 0.f, Csub = 0.f, Cpos = 0.f;

        for (int p = grp; p < T; p += 16) {
            int r1 = (int)((sqrtf(8.0f * (float)p + 1.0f) - 1.0f) * 0.5f);
            while ((r1 + 1) * (r1 + 2) / 2 <= p) ++r1;
            while (r1 * (r1 + 1) / 2 > p) --r1;
            int c = p - r1 * (r1 + 1) / 2;

            const unsigned short* ru = rc + r1 * DDIM + l16 * 16;
            const unsigned short* rv = rc + c  * DDIM + l16 * 16;
            float d = 0.f;
            #pragma unroll
            for (int h = 0; h < 2; ++h) {
                u16x8 a8 = *reinterpret_cast<const u16x8*>(ru + h * 8);
                u16x8 b8 = *reinterpret_cast<const u16x8*>(rv + h * 8);
                #pragma unroll
                for (int e = 0; e < 8; ++e)
                    d = fmaf(bf2f(a8[e]), bf2f(b8[e]), d);
            }
            d += __shfl_xor(d, 1);
            d += __shfl_xor(d, 2);
            d += __shfl_xor(d, 4);
            d += __shfl_xor(d, 8);

            if (l16 == 0) {
                // match the main epilogue's formula shape for best cancellation
                float vn1 = fmaf(sAPi[r1], d + sBsi[c],  sCi[r1]);   // v_neg(u,v)
                if (r1 == c) {
                    // diagonal: main counted it once as a neg; no pos term
                    Ssub += fmaxf(vn1, 0.f); Csub += (vn1 > 0.f);
                } else {
                    float vn2 = fmaf(sAPi[c], d + sBsi[r1], sCi[c]); // v_neg(v,u)
                    Ssub += fmaxf(vn1, 0.f) + fmaxf(vn2, 0.f);
                    Csub += (vn1 > 0.f); Csub += (vn2 > 0.f);
                    float rawfull = d + sBsi[r1] + sBsi[c];
                    float vp1 = fmaf(-sAPi[r1], rawfull, -0.01f);    // d_uv - 0.01
                    float vp2 = fmaf(-sAPi[c],  rawfull, -0.01f);    // d_vu - 0.01
                    Spos += fmaxf(vp1, 0.f) + fmaxf(vp2, 0.f);
                    Cpos += (vp1 > 0.f); Cpos += (vp2 > 0.f);
                }
            }
        }

        #pragma unroll
        for (int off = 32; off >= 1; off >>= 1) {
            Ssub += __shfl_down(Ssub, off);
            Csub += __shfl_down(Csub, off);
            Spos += __shfl_down(Spos, off);
            Cpos += __shfl_down(Cpos, off);
        }
        if (lane == 0) {
            redbuf[wave][0] = Ssub; redbuf[wave][1] = Csub;
            redbuf[wave][2] = Spos; redbuf[wave][3] = Cpos;
        }
        __syncthreads();
        if (tid == 0) {
            float a0 = redbuf[0][0] + redbuf[1][0] + redbuf[2][0] + redbuf[3][0];
            float a1 = redbuf[0][1] + redbuf[1][1] + redbuf[2][1] + redbuf[3][1];
            float a2 = redbuf[0][2] + redbuf[1][2] + redbuf[2][2] + redbuf[3][2];
            float a3 = redbuf[0][3] + redbuf[1][3] + redbuf[2][3] + redbuf[3][3];
            atomicAdd(accum + 2, a0);
            atomicAdd(accum + 3, a1);
            atomicAdd(accum + 4, a2);
            atomicAdd(accum + 5, a3);
            atomicAdd(accum + 6, rrp);
        }
    } else {
        // ---------------- GEMM path ----------------
        unsigned short* As = smem;
        unsigned short* Bs = smem + BT * BK;
        int wr = (wave >> 1) * 64;
        int wc = (wave & 1) * 64;

        // decode triangular block id -> (bi, bj), bi <= bj
        int t = blockIdx.x - NCLS;
        int bi = (int)((2.0f * GT + 1.0f
                        - sqrtf((2.0f * GT + 1.0f) * (2.0f * GT + 1.0f) - 8.0f * (float)t)) * 0.5f);
        while ((bi + 1) * GT - ((bi + 1) * bi) / 2 <= t) ++bi;
        while (bi * GT - (bi * (bi - 1)) / 2 > t) --bi;
        int bj = bi + (t - (bi * GT - (bi * (bi - 1)) / 2));
        int rowBase = bi * BT, colBase = bj * BT;
        bool diag = (bi == bj);

        // stage per-row / per-col epilogue constants (covered by first K-loop barrier)
        if (tid < BT) {
            int gi = rowBase + tid;
            sAPi[tid] = aP[gi]; sBsi[tid] = bs[gi]; sCi[tid] = cA[gi];
        } else {
            int tt = tid - BT;
            int gj = colBase + tt;
            sAPj[tt] = aP[gj]; sBsj[tt] = bs[gj]; sCj[tt] = cA[gj];
        }

        // staging addresses: chunk q = p*256+tid; logical (row=q>>3, slot=q&7),
        // slot holds k-chunk kc = slot ^ (row&7)  (XOR swizzle, conflict-free frag reads)
        const unsigned short* gA[4];
        const unsigned short* gB[4];
        unsigned short* lpA[4];
        unsigned short* lpB[4];
        #pragma unroll
        for (int p = 0; p < 4; ++p) {
            int q   = p * 256 + tid;
            int row = q >> 3;
            int kc  = (q & 7) ^ (row & 7);
            gA[p] = ebf + (size_t)(rowBase + row) * DDIM + kc * 8;
            gB[p] = ebf + (size_t)(colBase + row) * DDIM + kc * 8;
            lpA[p] = As + q * 8;
            lpB[p] = Bs + q * 8;
        }

        // fragment LDS offsets (elems), swizzle-aware
        int mrow = lane & 15;
        int kch  = lane >> 4;          // 16B k-chunk within half
        int offA[4][2], offB[4][2];
        #pragma unroll
        for (int t4 = 0; t4 < 4; ++t4) {
            int rA = wr + t4 * 16 + mrow;
            int rB = wc + t4 * 16 + mrow;
            #pragma unroll
            for (int h = 0; h < 2; ++h) {
                offA[t4][h] = (rA * 8 + ((h * 4 + kch) ^ (rA & 7))) * 8;
                offB[t4][h] = (rB * 8 + ((h * 4 + kch) ^ (rB & 7))) * 8;
            }
        }

        f32x4 acc[4][4];
        #pragma unroll
        for (int a = 0; a < 4; ++a)
            #pragma unroll
            for (int b = 0; b < 4; ++b)
                acc[a][b] = (f32x4){0.f, 0.f, 0.f, 0.f};

        for (int it = 0; it < 4; ++it) {
            #pragma unroll
            for (int p = 0; p < 4; ++p) {
                glds16(gA[p], lpA[p]);
                glds16(gB[p], lpB[p]);
                gA[p] += BK;
                gB[p] += BK;
            }
            asm volatile("s_waitcnt vmcnt(0)" ::: "memory");
            __syncthreads();

            #pragma unroll
            for (int h = 0; h < 2; ++h) {
                bf16x8 aF[4], bF[4];
                #pragma unroll
                for (int t4 = 0; t4 < 4; ++t4) {
                    aF[t4] = *reinterpret_cast<const bf16x8*>(As + offA[t4][h]);
                    bF[t4] = *reinterpret_cast<const bf16x8*>(Bs + offB[t4][h]);
                }
                #pragma unroll
                for (int ti = 0; ti < 4; ++ti)
                    #pragma unroll
                    for (int tj = 0; tj < 4; ++tj)
                        acc[ti][tj] = __builtin_amdgcn_mfma_f32_16x16x32_bf16(aF[ti], bF[tj], acc[ti][tj], 0, 0, 0);
            }
            __syncthreads();
        }

        // Epilogue: neg treatment for EVERY ordered pair (no labels here).
        // v_neg(i,j) = fmaf(aP_i, raw + bs_j, c_i);  off-diag blocks do both sides.
        int subr = (lane >> 4) * 4;
        int cj   = lane & 15;

        float aPC[4], bsC[4], cC[4];
        #pragma unroll
        for (int tj = 0; tj < 4; ++tj) {
            int lj = wc + tj * 16 + cj;
            aPC[tj] = sAPj[lj]; bsC[tj] = sBsj[lj]; cC[tj] = sCj[lj];
        }

        float S = 0.f;
        unsigned C = 0u;

        if (!diag) {
            #pragma unroll
            for (int ti = 0; ti < 4; ++ti) {
                #pragma unroll
                for (int r = 0; r < 4; ++r) {
                    int li = wr + ti * 16 + subr + r;
                    float aR = sAPi[li], bR = sBsi[li], cR = sCi[li];
                    #pragma unroll
                    for (int tj = 0; tj < 4; ++tj) {
                        float raw = acc[ti][tj][r];
                        float v1 = fmaf(aR, raw + bsC[tj], cR);       // side (i,j)
                        float v2 = fmaf(aPC[tj], raw + bR, cC[tj]);   // side (j,i)
                        S += fmaxf(v1, 0.f) + fmaxf(v2, 0.f);
                        C += (v1 > 0.f);
                        C += (v2 > 0.f);
                    }
                }
            }
        } else {
            #pragma unroll
            for (int ti = 0; ti < 4; ++ti) {
                #pragma unroll
                for (int r = 0; r < 4; ++r) {
                    int li = wr + ti * 16 + subr + r;
                    float aR = sAPi[li], cR = sCi[li];
                    #pragma unroll
                    for (int tj = 0; tj < 4; ++tj) {
                        float raw = acc[ti][tj][r];
                        float v1 = fmaf(aR, raw + bsC[tj], cR);
                        S += fmaxf(v1, 0.f);
                        C += (v1 > 0.f);
                    }
                }
            }
        }

        #pragma unroll
        for (int off = 32; off >= 1; off >>= 1) {
            S += __shfl_down(S, off);
            C += __shfl_down(C, off);
        }
        if (lane == 0) { redbuf[wave][0] = S; redbuf[wave][1] = (float)C; }
        __syncthreads();
        if (tid == 0) {
            float a0 = redbuf[0][0] + redbuf[1][0] + redbuf[2][0] + redbuf[3][0];
            float a1 = redbuf[0][1] + redbuf[1][1] + redbuf[2][1] + redbuf[3][1];
            atomicAdd(accum + 0, a0);
            atomicAdd(accum + 1, a1);
        }
    }

    // ---------------- last-block-done finalize ----------------
    if (tid == 0) {
        __threadfence();
        unsigned old = atomicAdd((unsigned*)(accum + 7), 1u);
        if (old == NTOT - 1) {
            // coherent reads of the accumulators via device-scope RMW
            float sAll = atomicAdd(accum + 0, 0.f);
            float cAll = atomicAdd(accum + 1, 0.f);
            float sSub = atomicAdd(accum + 2, 0.f);
            float cSub = atomicAdd(accum + 3, 0.f);
            float sPos = atomicAdd(accum + 4, 0.f);
            float cPos = atomicAdd(accum + 5, 0.f);
            float rr   = atomicAdd(accum + 6, 0.f);
            float Sn = sAll - sSub;
            float Cn = cAll - cSub;
            // guard: count==0 -> reference yields sum/1e-12 with sum==0 -> 0
            float pos = (cPos > 0.5f) ? sPos / (cPos + 1e-12f) : 0.0f;
            float neg = (Cn   > 0.5f) ? Sn   / (Cn   + 1e-12f) : 0.0f;
            out[0] = pos + neg + rr * (0.1f / (float)NROWS);
        }
    }
}

extern "C" void kernel_launch(void* const* d_in, const int* in_sizes, int n_in,
                              void* d_out, int out_size, void* d_ws, size_t ws_size,
                              hipStream_t stream) {
    const float* embeds = (const float*)d_in[0];
    const int*   labels = (const int*)d_in[1];
    float* out = (float*)d_out;

    char* ws = (char*)d_ws;
    unsigned short* ebf = (unsigned short*)ws;                       // 4 MB
    float* aP    = (float*)(ws + (size_t)NROWS * DDIM * 2);
    float* bs    = aP + NROWS;
    float* cA    = bs + NROWS;
    float* rabs  = cA + NROWS;
    float* accum = rabs + NROWS;                                     // 8 floats

    rowstats_kernel<<<NROWS / 4, 256, 0, stream>>>(embeds, ebf, aP, bs, cA, rabs, accum);

    snr_main_kernel<<<NTOT, 256, 0, stream>>>(ebf, aP, bs, cA, labels, rabs, accum, out);
}

// Round 6
// 146.821 us; speedup vs baseline: 1.7959x; 1.3684x over previous
//
#include <hip/hip_runtime.h>

#define NROWS 8192
#define DDIM 256
#define BT 128
#define BK 64
#define GT (NROWS / BT)            // 64 tile-rows
#define NBT (GT * (GT + 1) / 2)    // 2080 upper-triangle blocks

using bf16x8 = __attribute__((ext_vector_type(8))) __bf16;
using f32x4  = __attribute__((ext_vector_type(4))) float;

__device__ __forceinline__ void glds16(const unsigned short* g, unsigned short* l) {
    // async global->LDS DMA, 16B/lane; LDS dest = wave-uniform base + lane*16
    __builtin_amdgcn_global_load_lds(
        (const __attribute__((address_space(1))) unsigned int*)g,
        (__attribute__((address_space(3))) unsigned int*)l,
        16, 0, 0);
}

__device__ __forceinline__ unsigned short f2bf(float f) {
    unsigned int b = __float_as_uint(f);
    unsigned int r = b + 0x7fffu + ((b >> 16) & 1u);
    return (unsigned short)(r >> 16);
}

// Kernel 1: one wave per row. Normalize, CENTER (e - mean), emit bf16 e~,
// and per-row epilogue constants:
//   dist_ij = (b_i + b_j - (e~_i . e~_j)/128) / b_i
//   v_neg(i,j) = 0.2 - dist_ij = fmaf(aP_i, raw + bs_j, c_i),  raw = MFMA acc
//   with aP = (1/b)/128, bs = -128*b, c = aP*bs + 0.2
//   v_pos(i,j) = dist_ij - 0.01 = 0.19 - v_neg(i,j)
__global__ __launch_bounds__(256) void rowstats_kernel(
    const float* __restrict__ x, unsigned short* __restrict__ ebf,
    float* __restrict__ aP, float* __restrict__ bs,
    float* __restrict__ cA, float* __restrict__ rabs)
{
    int wave = threadIdx.x >> 6;
    int lane = threadIdx.x & 63;
    int row  = blockIdx.x * 4 + wave;

    const float4 v = reinterpret_cast<const float4*>(x + (size_t)row * DDIM)[lane];
    float ss = v.x * v.x + v.y * v.y + v.z * v.z + v.w * v.w;
    float sm = v.x + v.y + v.z + v.w;
    #pragma unroll
    for (int off = 32; off >= 1; off >>= 1) {
        ss += __shfl_xor(ss, off);
        sm += __shfl_xor(sm, off);
    }
    float invn = 1.0f / sqrtf(ss);
    float m = sm * invn * (1.0f / DDIM);

    ushort4 o;
    o.x = f2bf(v.x * invn - m);
    o.y = f2bf(v.y * invn - m);
    o.z = f2bf(v.z * invn - m);
    o.w = f2bf(v.w * invn - m);
    reinterpret_cast<ushort4*>(ebf + (size_t)row * DDIM)[lane] = o;

    if (lane == 0) {
        float s  = ss * invn * invn * (1.0f / DDIM);
        float b  = s - m * m;
        float a  = 1.0f / b;
        float ap = a * (1.0f / 128.0f);
        float bv = -128.0f * b;
        aP[row]   = ap;
        bs[row]   = bv;
        cA[row]   = fmaf(ap, bv, 0.2f);
        rabs[row] = fabsf(sm * invn);
    }
}

// Kernel 2: upper-triangle E~.E~^T bf16 MFMA GEMM. Epilogue: unconditional
// neg treatment for every ordered pair (2 VALU/side), plus a RARE inline
// same-label correction behind a wave-uniform __ballot branch (~12% of
// 64-element sites contain any same-label pair at 512 classes).
// Per-block partials: {Sneg, Cneg, Spos, Cpos} with same-label neg terms
// already subtracted in-lane (exact cancellation - same acc value).
__global__ __launch_bounds__(256) void snr_gemm_kernel(
    const unsigned short* __restrict__ ebf,
    const float* __restrict__ aP, const float* __restrict__ bs,
    const float* __restrict__ cA, const int* __restrict__ labels,
    float* __restrict__ partials)
{
    __shared__ __align__(16) unsigned short As[BT * BK];   // 16 KB, swizzled chunks
    __shared__ __align__(16) unsigned short Bs[BT * BK];   // 16 KB
    __shared__ float sAPi[BT], sBsi[BT], sCi[BT];
    __shared__ float sAPj[BT], sBsj[BT], sCj[BT];
    __shared__ int   sLi[BT], sLj[BT];
    __shared__ float redbuf[4][4];

    int tid  = threadIdx.x;
    int lane = tid & 63;
    int wave = tid >> 6;
    int wr = (wave >> 1) * 64;
    int wc = (wave & 1) * 64;

    // decode triangular block id -> (bi, bj), bi <= bj
    int t = blockIdx.x;
    int bi = (int)((2.0f * GT + 1.0f
                    - sqrtf((2.0f * GT + 1.0f) * (2.0f * GT + 1.0f) - 8.0f * (float)t)) * 0.5f);
    while ((bi + 1) * GT - ((bi + 1) * bi) / 2 <= t) ++bi;
    while (bi * GT - (bi * (bi - 1)) / 2 > t) --bi;
    int bj = bi + (t - (bi * GT - (bi * (bi - 1)) / 2));
    int rowBase = bi * BT, colBase = bj * BT;
    bool diag = (bi == bj);

    // stage per-row / per-col epilogue constants (covered by first K-loop barrier)
    if (tid < BT) {
        int gi = rowBase + tid;
        sAPi[tid] = aP[gi]; sBsi[tid] = bs[gi]; sCi[tid] = cA[gi];
        sLi[tid] = labels[gi];
    } else {
        int tt = tid - BT;
        int gj = colBase + tt;
        sAPj[tt] = aP[gj]; sBsj[tt] = bs[gj]; sCj[tt] = cA[gj];
        sLj[tt] = labels[gj];
    }

    // staging addresses: chunk q = p*256+tid; logical (row=q>>3, slot=q&7),
    // slot holds k-chunk kc = slot ^ (row&7)  (XOR swizzle, conflict-free frag reads)
    const unsigned short* gA[4];
    const unsigned short* gB[4];
    unsigned short* lpA[4];
    unsigned short* lpB[4];
    #pragma unroll
    for (int p = 0; p < 4; ++p) {
        int q   = p * 256 + tid;
        int row = q >> 3;
        int kc  = (q & 7) ^ (row & 7);
        gA[p] = ebf + (size_t)(rowBase + row) * DDIM + kc * 8;
        gB[p] = ebf + (size_t)(colBase + row) * DDIM + kc * 8;
        lpA[p] = As + q * 8;
        lpB[p] = Bs + q * 8;
    }

    // fragment LDS offsets (elems), swizzle-aware
    int mrow = lane & 15;
    int kch  = lane >> 4;          // 16B k-chunk within half
    int offA[4][2], offB[4][2];
    #pragma unroll
    for (int t4 = 0; t4 < 4; ++t4) {
        int rA = wr + t4 * 16 + mrow;
        int rB = wc + t4 * 16 + mrow;
        #pragma unroll
        for (int h = 0; h < 2; ++h) {
            offA[t4][h] = (rA * 8 + ((h * 4 + kch) ^ (rA & 7))) * 8;
            offB[t4][h] = (rB * 8 + ((h * 4 + kch) ^ (rB & 7))) * 8;
        }
    }

    f32x4 acc[4][4];
    #pragma unroll
    for (int a = 0; a < 4; ++a)
        #pragma unroll
        for (int b = 0; b < 4; ++b)
            acc[a][b] = (f32x4){0.f, 0.f, 0.f, 0.f};

    for (int it = 0; it < 4; ++it) {
        #pragma unroll
        for (int p = 0; p < 4; ++p) {
            glds16(gA[p], lpA[p]);
            glds16(gB[p], lpB[p]);
            gA[p] += BK;
            gB[p] += BK;
        }
        asm volatile("s_waitcnt vmcnt(0)" ::: "memory");
        __syncthreads();

        #pragma unroll
        for (int h = 0; h < 2; ++h) {
            bf16x8 aF[4], bF[4];
            #pragma unroll
            for (int t4 = 0; t4 < 4; ++t4) {
                aF[t4] = *reinterpret_cast<const bf16x8*>(As + offA[t4][h]);
                bF[t4] = *reinterpret_cast<const bf16x8*>(Bs + offB[t4][h]);
            }
            #pragma unroll
            for (int ti = 0; ti < 4; ++ti)
                #pragma unroll
                for (int tj = 0; tj < 4; ++tj)
                    acc[ti][tj] = __builtin_amdgcn_mfma_f32_16x16x32_bf16(aF[ti], bF[tj], acc[ti][tj], 0, 0, 0);
        }
        __syncthreads();
    }

    // ---------------- epilogue ----------------
    int subr = (lane >> 4) * 4;
    int cj   = lane & 15;

    float aPC[4], bsC[4], cC[4];
    int LCj[4];
    #pragma unroll
    for (int tj = 0; tj < 4; ++tj) {
        int lj = wc + tj * 16 + cj;
        aPC[tj] = sAPj[lj]; bsC[tj] = sBsj[lj]; cC[tj] = sCj[lj];
        LCj[tj] = sLj[lj];
    }

    float S = 0.f, Ssub = 0.f, Spos = 0.f;
    unsigned C = 0u, Csub = 0u, Cpos = 0u;

    if (!diag) {
        #pragma unroll
        for (int ti = 0; ti < 4; ++ti) {
            #pragma unroll
            for (int r = 0; r < 4; ++r) {
                int li = wr + ti * 16 + subr + r;
                float aR = sAPi[li], bR = sBsi[li], cR = sCi[li];
                int LR = sLi[li];
                #pragma unroll
                for (int tj = 0; tj < 4; ++tj) {
                    float raw = acc[ti][tj][r];
                    float v1 = fmaf(aR, raw + bsC[tj], cR);       // v_neg (i,j)
                    float v2 = fmaf(aPC[tj], raw + bR, cC[tj]);   // v_neg (j,i)
                    S += fmaxf(v1, 0.f) + fmaxf(v2, 0.f);
                    C += (v1 > 0.f);
                    C += (v2 > 0.f);
                    bool same = (LR == LCj[tj]);
                    if (__ballot(same)) {                          // rare (~12% of sites)
                        Ssub += same ? fmaxf(v1, 0.f) + fmaxf(v2, 0.f) : 0.f;
                        Csub += same ? (unsigned)(v1 > 0.f) + (unsigned)(v2 > 0.f) : 0u;
                        float vp1 = 0.19f - v1;                    // dist_ij - 0.01
                        float vp2 = 0.19f - v2;                    // dist_ji - 0.01
                        Spos += same ? fmaxf(vp1, 0.f) + fmaxf(vp2, 0.f) : 0.f;
                        Cpos += same ? (unsigned)(vp1 > 0.f) + (unsigned)(vp2 > 0.f) : 0u;
                    }
                }
            }
        }
    } else {
        #pragma unroll
        for (int ti = 0; ti < 4; ++ti) {
            #pragma unroll
            for (int r = 0; r < 4; ++r) {
                int li = wr + ti * 16 + subr + r;
                float aR = sAPi[li], cR = sCi[li];
                int LR = sLi[li];
                #pragma unroll
                for (int tj = 0; tj < 4; ++tj) {
                    float raw = acc[ti][tj][r];
                    float v1 = fmaf(aR, raw + bsC[tj], cR);
                    S += fmaxf(v1, 0.f);
                    C += (v1 > 0.f);
                    bool same = (LR == LCj[tj]);                  // includes self (li==lj)
                    if (__ballot(same)) {
                        Ssub += same ? fmaxf(v1, 0.f) : 0.f;
                        Csub += same ? (unsigned)(v1 > 0.f) : 0u;
                        int lj = wc + tj * 16 + cj;
                        bool offd = same && (li != lj);           // eye excluded from pos
                        float vp1 = 0.19f - v1;
                        Spos += offd ? fmaxf(vp1, 0.f) : 0.f;
                        Cpos += offd ? (unsigned)(vp1 > 0.f) : 0u;
                    }
                }
            }
        }
    }

    // per-lane corrected neg, then block reduction of {Sn, Cn, Spos, Cpos}
    float Sn = S - Ssub;
    float Cn = (float)C - (float)Csub;
    float Sp = Spos;
    float Cp = (float)Cpos;

    #pragma unroll
    for (int off = 32; off >= 1; off >>= 1) {
        Sn += __shfl_down(Sn, off);
        Cn += __shfl_down(Cn, off);
        Sp += __shfl_down(Sp, off);
        Cp += __shfl_down(Cp, off);
    }
    if (lane == 0) {
        redbuf[wave][0] = Sn; redbuf[wave][1] = Cn;
        redbuf[wave][2] = Sp; redbuf[wave][3] = Cp;
    }
    __syncthreads();
    if (tid < 4) {
        partials[blockIdx.x * 4 + tid] =
            redbuf[0][tid] + redbuf[1][tid] + redbuf[2][tid] + redbuf[3][tid];
    }
}

// Kernel 3: reduce per-block partials + per-row reg terms, emit scalar loss.
// Guard: if a count sums to exactly 0, the true masked sum is 0 too
// (reference yields 0/1e-12 = 0) -> emit 0 instead of residual/1e-12.
__global__ __launch_bounds__(256) void finalize_kernel(
    const float* __restrict__ partials, const float* __restrict__ rabs,
    float* __restrict__ out)
{
    int tid = threadIdx.x;
    float s0 = 0, s1 = 0, s2 = 0, s3 = 0, rr = 0;
    for (int i = tid; i < NBT; i += 256) {
        float4 p = reinterpret_cast<const float4*>(partials)[i];
        s0 += p.x; s1 += p.y; s2 += p.z; s3 += p.w;
    }
    for (int i = tid; i < NROWS; i += 256) rr += rabs[i];

    #pragma unroll
    for (int off = 32; off >= 1; off >>= 1) {
        s0 += __shfl_down(s0, off);
        s1 += __shfl_down(s1, off);
        s2 += __shfl_down(s2, off);
        s3 += __shfl_down(s3, off);
        rr += __shfl_down(rr, off);
    }
    __shared__ float red[4][5];
    int wave = tid >> 6, lane = tid & 63;
    if (lane == 0) {
        red[wave][0] = s0; red[wave][1] = s1; red[wave][2] = s2;
        red[wave][3] = s3; red[wave][4] = rr;
    }
    __syncthreads();
    if (tid == 0) {
        float a0 = 0, a1 = 0, a2 = 0, a3 = 0, a4 = 0;
        #pragma unroll
        for (int w = 0; w < 4; ++w) {
            a0 += red[w][0]; a1 += red[w][1]; a2 += red[w][2];
            a3 += red[w][3]; a4 += red[w][4];
        }
        float neg = (a1 > 0.5f) ? a0 / (a1 + 1e-12f) : 0.0f;
        float pos = (a3 > 0.5f) ? a2 / (a3 + 1e-12f) : 0.0f;
        out[0] = pos + neg + a4 * (0.1f / (float)NROWS);
    }
}

extern "C" void kernel_launch(void* const* d_in, const int* in_sizes, int n_in,
                              void* d_out, int out_size, void* d_ws, size_t ws_size,
                              hipStream_t stream) {
    const float* embeds = (const float*)d_in[0];
    const int*   labels = (const int*)d_in[1];
    float* out = (float*)d_out;

    char* ws = (char*)d_ws;
    unsigned short* ebf = (unsigned short*)ws;              // 4 MB
    float* aP   = (float*)(ws + (size_t)NROWS * DDIM * 2);
    float* bs   = aP + NROWS;
    float* cA   = bs + NROWS;
    float* rabs = cA + NROWS;
    float* partials = rabs + NROWS;                         // NBT*4 floats

    rowstats_kernel<<<NROWS / 4, 256, 0, stream>>>(embeds, ebf, aP, bs, cA, rabs);

    snr_gemm_kernel<<<NBT, 256, 0, stream>>>(ebf, aP, bs, cA, labels, partials);

    finalize_kernel<<<1, 256, 0, stream>>>(partials, rabs, out);
}